// Round 1
// 620.570 us; speedup vs baseline: 1.1331x; 1.1331x over previous
//
#include <hip/hip_runtime.h>
#include <stdint.h>
#include <stddef.h>

// MinGRU: B=8, S=4096, DX=DH=1024. All inputs fp32, output fp32.
// R7 (from R6 @703us): attack the GEMM stall pattern seen in rocprof
// (MfmaUtil 26 + VALUBusy 27 = 53% busy; FETCH 270MB vs ~68MB ideal):
//  1. Double-buffered LDS in both GEMMs, STAGE(next) issued BEFORE compute
//     of current tile, ONE barrier per K-step (was 2). Hides global->LDS
//     latency under the 32-MFMA compute phase (T3-minimum recipe).
//  2. Bijective XCD-chunked blockIdx swizzle: XCD j owns M-tiles
//     [32j,32j+32), sweeping all 8 N-tiles of an M-tile consecutively ->
//     X panel becomes an L2 hit for 7/8 consumers, weights stay resident.
//  3. Wave-parallel checkers (1 wave/sample, coalesced k, shuffle-reduce)
//     instead of serial per-thread 1024-iter dots on 4 blocks.
//  4. Merged 3 weight-conversion launches into one; grid-stride everywhere
//     (R5 coverage-bug class stays dead).
// Scan phases + scalar fallbacks unchanged.

typedef __bf16 bf16;
typedef __bf16 bf16x8 __attribute__((ext_vector_type(8)));
typedef float f32x4 __attribute__((ext_vector_type(4)));

#define DEV __device__ __forceinline__

DEV void gload_lds16(const bf16* g, bf16* l) {
  // per-lane gptr; LDS dest = wave-uniform base + lane*16B (implicit scatter)
  __builtin_amdgcn_global_load_lds((const __attribute__((address_space(1))) void*)g,
                                   (__attribute__((address_space(3))) void*)l,
                                   16, 0, 0);
}

// ---------------- fp32 -> bf16 conversion (grid-stride) -----------------------
__global__ __launch_bounds__(256)
void conv_b(const float* __restrict__ src, bf16* __restrict__ dst, int n4) {
  const int stride = gridDim.x * 256;
  for (int i = blockIdx.x * 256 + threadIdx.x; i < n4; i += stride) {
    float4 v = ((const float4*)src)[i];
    bf16 o[4] = {(bf16)v.x, (bf16)v.y, (bf16)v.z, (bf16)v.w};
    *(uint64_t*)(dst + 4 * (size_t)i) = *(uint64_t*)o;
  }
}

// three 1024x1024 weights in one launch (each = 262144 float4 groups)
__global__ __launch_bounds__(256)
void conv_w3(const float* __restrict__ s0, const float* __restrict__ s1,
             const float* __restrict__ s2,
             bf16* __restrict__ d0, bf16* __restrict__ d1, bf16* __restrict__ d2) {
  const int stride = gridDim.x * 256;
  for (int i = blockIdx.x * 256 + threadIdx.x; i < 786432; i += stride) {
    const float* s; bf16* d; int off;
    if (i < 262144)      { s = s0; d = d0; off = i; }
    else if (i < 524288) { s = s1; d = d1; off = i - 262144; }
    else                 { s = s2; d = d2; off = i - 524288; }
    float4 v = ((const float4*)s)[off];
    bf16 o[4] = {(bf16)v.x, (bf16)v.y, (bf16)v.z, (bf16)v.w};
    *(uint64_t*)(d + 4 * (size_t)off) = *(uint64_t*)o;
  }
}

// XCD-chunked bijective swizzle for grid (8, 256): dispatch index d (x fastest)
// -> XCD d&7 owns M-tiles [32*(d&7), 32*(d&7)+32), N-tile fastest within.
DEV void xcd_tiles(int bx, int by, int& tileM, int& tileN) {
  const int d = by * 8 + bx;
  const int xcd = d & 7;
  const int i = d >> 3;              // 0..255
  tileM = (xcd * 32 + (i >> 3)) * 128;
  tileN = (i & 7) * 128;
}

// ---------------- gate GEMM: dual output, 128x128 tile, BK=32, dbuf DMA -------
__global__ __launch_bounds__(256, 2)
void gate_gemm(const bf16* __restrict__ X,
               const bf16* __restrict__ Wz, const bf16* __restrict__ Wh,
               const float* __restrict__ bzf, const float* __restrict__ bhf,
               bf16* __restrict__ aB, bf16* __restrict__ vB) {
  __shared__ __align__(16) bf16 As [2 * 4096];   // 2 x 128x32
  __shared__ __align__(16) bf16 Bzs[2 * 4096];
  __shared__ __align__(16) bf16 Bhs[2 * 4096];

  const int lane = threadIdx.x & 63;
  const int wave = threadIdx.x >> 6;
  const int wm = wave >> 1, wn = wave & 1;    // 2x2 waves of 64x64
  int tileM, tileN;
  xcd_tiles(blockIdx.x, blockIdx.y, tileM, tileN);
  const int q = lane >> 4, r = lane & 15;     // MFMA quad / m(or n)-in-frag
  const int srow = lane >> 2;                 // staging row within 16-row chunk
  const int scol = (lane & 3) * 8;            // staging k-offset (elements)

  const bf16* ga[2]; const bf16* gz[2]; const bf16* gh[2];
  bf16* la[2]; bf16* lz[2]; bf16* lh[2];
#pragma unroll
  for (int j = 0; j < 2; ++j) {
    const int cid = j * 4 + wave;             // 0..7 -> 16-row chunk
    const int row = cid * 16 + srow;
    ga[j] = X  + (size_t)(tileM + row) * 1024 + scol;
    gz[j] = Wz + (size_t)(tileN + row) * 1024 + scol;
    gh[j] = Wh + (size_t)(tileN + row) * 1024 + scol;
    la[j] = As  + cid * 512;                  // wave-uniform LDS base (buf 0)
    lz[j] = Bzs + cid * 512;
    lh[j] = Bhs + cid * 512;
  }

  const bf16* pA[4]; const bf16* pBz[4]; const bf16* pBh[4];
#pragma unroll
  for (int f = 0; f < 4; ++f) {
    pA[f]  = As  + (wm * 64 + f * 16 + r) * 32 + q * 8;  // A[m=r][k=q*8+j]
    pBz[f] = Bzs + (wn * 64 + f * 16 + r) * 32 + q * 8;  // B[n=r][k=q*8+j]
    pBh[f] = Bhs + (wn * 64 + f * 16 + r) * 32 + q * 8;
  }

  f32x4 accz[4][4], acch[4][4];
#pragma unroll
  for (int i = 0; i < 4; ++i)
#pragma unroll
    for (int j = 0; j < 4; ++j) {
      accz[i][j] = (f32x4){0.f, 0.f, 0.f, 0.f};
      acch[i][j] = (f32x4){0.f, 0.f, 0.f, 0.f};
    }

  auto STAGE = [&](int buf, int k0) {
    const int bo = buf * 4096;
#pragma unroll
    for (int j = 0; j < 2; ++j) {
      gload_lds16(ga[j] + k0, la[j] + bo);
      gload_lds16(gz[j] + k0, lz[j] + bo);
      gload_lds16(gh[j] + k0, lh[j] + bo);
    }
  };
  auto COMPUTE = [&](int buf) {
    const int bo = buf * 4096;
    bf16x8 af[4];
#pragma unroll
    for (int fm = 0; fm < 4; ++fm) af[fm] = *(const bf16x8*)(pA[fm] + bo);
#pragma unroll
    for (int fn = 0; fn < 4; ++fn) {
      bf16x8 bz8 = *(const bf16x8*)(pBz[fn] + bo);
      bf16x8 bh8 = *(const bf16x8*)(pBh[fn] + bo);
#pragma unroll
      for (int fm = 0; fm < 4; ++fm) {
        accz[fm][fn] = __builtin_amdgcn_mfma_f32_16x16x32_bf16(af[fm], bz8, accz[fm][fn], 0, 0, 0);
        acch[fm][fn] = __builtin_amdgcn_mfma_f32_16x16x32_bf16(af[fm], bh8, acch[fm][fn], 0, 0, 0);
      }
    }
  };

  // prologue stage, then: barrier -> stage(next) -> compute(cur).
  // The barrier's vmcnt(0) drain now waits on loads issued a full compute
  // phase ago (latency hidden), instead of loads issued immediately before.
  STAGE(0, 0);
  int cur = 0;
  for (int t = 0; t < 31; ++t) {
    __syncthreads();
    STAGE(cur ^ 1, (t + 1) * 32);
    COMPUTE(cur);
    cur ^= 1;
  }
  __syncthreads();
  COMPUTE(cur);

  // C/D: col=lane&15, row=(lane>>4)*4+i  (m89/m91)
#pragma unroll
  for (int fn = 0; fn < 4; ++fn) {
    const int n = tileN + wn * 64 + fn * 16 + r;
    const float bzv = bzf[n], bhv = bhf[n];
#pragma unroll
    for (int fm = 0; fm < 4; ++fm) {
      const int m0 = tileM + wm * 64 + fm * 16 + q * 4;
#pragma unroll
      for (int i = 0; i < 4; ++i) {
        float kv = accz[fm][fn][i] + bzv;
        float tv = acch[fm][fn][i] + bhv;
        float e   = __expf(-kv);
        float inv = 1.f / (1.f + e);        // z = sigmoid(k)
        float a   = e * inv;                // 1-z = sigmoid(-k)
        float g   = (tv >= 0.f) ? (tv + 0.5f) : (1.f / (1.f + __expf(-tv)));
        size_t idx = (size_t)(m0 + i) * 1024 + n;
        aB[idx] = (bf16)a;
        vB[idx] = (bf16)(inv * g);
      }
    }
  }
}

// ---------------- gate check (wave-parallel) + scalar fallback ----------------
__global__ __launch_bounds__(256)
void chk_gate(const bf16* __restrict__ X,
              const bf16* __restrict__ Wz, const bf16* __restrict__ Wh,
              const float* __restrict__ bzf, const float* __restrict__ bhf,
              const bf16* __restrict__ aB, const bf16* __restrict__ vB,
              int* __restrict__ badA) {
  const int w = (blockIdx.x * 256 + threadIdx.x) >> 6;   // 0..1023 (grid 256)
  const int lane = threadIdx.x & 63;
  const int m = (w * 12347) & 32767;
  const int n = (w * 4099) & 1023;
  float kz = 0.f, kh = 0.f;
  for (int k = lane; k < 1024; k += 64) {                // coalesced 128B/wave
    float xv = (float)X[(size_t)m * 1024 + k];
    kz = fmaf(xv, (float)Wz[(size_t)n * 1024 + k], kz);
    kh = fmaf(xv, (float)Wh[(size_t)n * 1024 + k], kh);
  }
#pragma unroll
  for (int off = 32; off; off >>= 1) {
    kz += __shfl_xor(kz, off);
    kh += __shfl_xor(kh, off);
  }
  if (lane == 0) {
    kz += bzf[n]; kh += bhf[n];
    float e = __expf(-kz), inv = 1.f / (1.f + e);
    float a = e * inv;
    float g = (kh >= 0.f) ? (kh + 0.5f) : (1.f / (1.f + __expf(-kh)));
    float v = inv * g;
    size_t idx = (size_t)m * 1024 + n;
    int ok = (fabsf((float)aB[idx] - a) <= 0.04f) &&
             (fabsf((float)vB[idx] - v) <= 0.08f);       // NaN -> not ok
    if (!ok) atomicAdd(badA, 1);
  }
}

__global__ __launch_bounds__(256)
void fb_gate(const int* __restrict__ badA, const bf16* __restrict__ X,
             const bf16* __restrict__ Wz, const bf16* __restrict__ Wh,
             const float* __restrict__ bzf, const float* __restrict__ bhf,
             bf16* __restrict__ aB, bf16* __restrict__ vB) {
  if (*badA < 4) return;                           // MFMA path OK: no-op
  const int n = (blockIdx.x & 3) * 256 + threadIdx.x;
  const int m0 = (blockIdx.x >> 2) * 16;
  for (int mi = 0; mi < 16; ++mi) {
    const int m = m0 + mi;
    float kz = 0.f, kh = 0.f;
    for (int k = 0; k < 1024; ++k) {
      float xv = (float)X[(size_t)m * 1024 + k];
      kz = fmaf(xv, (float)Wz[(size_t)n * 1024 + k], kz);
      kh = fmaf(xv, (float)Wh[(size_t)n * 1024 + k], kh);
    }
    kz += bzf[n]; kh += bhf[n];
    float e = __expf(-kz), inv = 1.f / (1.f + e);
    float a = e * inv;
    float g = (kh >= 0.f) ? (kh + 0.5f) : (1.f / (1.f + __expf(-kh)));
    size_t idx = (size_t)m * 1024 + n;
    aB[idx] = (bf16)a;
    vB[idx] = (bf16)(inv * g);
  }
}

// ---------------- scan: h_t = a_t h_{t-1} + v_t, chunks L=64, 8-wide ----------
__global__ __launch_bounds__(256)
void scan_phase1(const bf16* __restrict__ aB, const bf16* __restrict__ vB,
                 float* __restrict__ Ac, float* __restrict__ Vc) {
  const int tid = blockIdx.x * 256 + threadIdx.x;  // B*C*(H/8) = 65536
  const int hg = tid & 127, c = (tid >> 7) & 63, b = tid >> 13;
  const size_t base = (size_t)(b * 4096 + c * 64) * 1024 + hg * 8;
  float A[8], V[8];
#pragma unroll
  for (int j = 0; j < 8; ++j) { A[j] = 1.f; V[j] = 0.f; }
#pragma unroll 8
  for (int t = 0; t < 64; ++t) {
    bf16x8 a8 = *(const bf16x8*)(aB + base + (size_t)t * 1024);
    bf16x8 v8 = *(const bf16x8*)(vB + base + (size_t)t * 1024);
#pragma unroll
    for (int j = 0; j < 8; ++j) {
      float a = (float)a8[j];
      V[j] = fmaf(a, V[j], (float)v8[j]);
      A[j] *= a;
    }
  }
  const size_t o = (size_t)(b * 64 + c) * 1024 + hg * 8;
#pragma unroll
  for (int j = 0; j < 8; ++j) { Ac[o + j] = A[j]; Vc[o + j] = V[j]; }
}

__global__ __launch_bounds__(256)
void scan_phase2(const float* __restrict__ Ac, const float* __restrict__ Vc,
                 float* __restrict__ Hin) {
  const int tid = blockIdx.x * 256 + threadIdx.x;  // B*H = 8192
  const int h = tid & 1023, b = tid >> 10;
  float carry = 0.f;
  for (int c = 0; c < 64; ++c) {
    const int idx = (b * 64 + c) * 1024 + h;
    Hin[idx] = carry;
    carry = fmaf(Ac[idx], carry, Vc[idx]);
  }
}

// hB aliases vB (in-place): no restrict on those, per-slot load->store order.
__global__ __launch_bounds__(256)
void scan_phase3(const bf16* __restrict__ aB, const bf16* vB,
                 const float* __restrict__ Hin, bf16* hB) {
  const int tid = blockIdx.x * 256 + threadIdx.x;  // 65536
  const int hg = tid & 127, c = (tid >> 7) & 63, b = tid >> 13;
  const size_t base = (size_t)(b * 4096 + c * 64) * 1024 + hg * 8;
  const size_t o = (size_t)(b * 64 + c) * 1024 + hg * 8;
  float hc[8];
#pragma unroll
  for (int j = 0; j < 8; ++j) hc[j] = Hin[o + j];
#pragma unroll 4
  for (int t = 0; t < 64; ++t) {
    bf16x8 a8 = *(const bf16x8*)(aB + base + (size_t)t * 1024);
    bf16x8 v8 = *(const bf16x8*)(vB + base + (size_t)t * 1024);
    bf16x8 h8;
#pragma unroll
    for (int j = 0; j < 8; ++j) {
      hc[j] = fmaf((float)a8[j], hc[j], (float)v8[j]);
      h8[j] = (bf16)hc[j];
    }
    *(bf16x8*)(hB + base + (size_t)t * 1024) = h8;
  }
}

// ---------------- out GEMM (dbuf DMA staging) -> fp32 output ------------------
__global__ __launch_bounds__(256, 2)
void out_gemm(const bf16* __restrict__ H, const bf16* __restrict__ Wo,
              const float* __restrict__ bof, float* __restrict__ O) {
  __shared__ __align__(16) bf16 As[2 * 4096];
  __shared__ __align__(16) bf16 Bs[2 * 4096];

  const int lane = threadIdx.x & 63;
  const int wave = threadIdx.x >> 6;
  const int wm = wave >> 1, wn = wave & 1;
  int tileM, tileN;
  xcd_tiles(blockIdx.x, blockIdx.y, tileM, tileN);
  const int q = lane >> 4, r = lane & 15;
  const int srow = lane >> 2;
  const int scol = (lane & 3) * 8;

  const bf16* ga[2]; const bf16* gb[2]; bf16* la[2]; bf16* lb[2];
#pragma unroll
  for (int j = 0; j < 2; ++j) {
    const int cid = j * 4 + wave;
    const int row = cid * 16 + srow;
    ga[j] = H  + (size_t)(tileM + row) * 1024 + scol;
    gb[j] = Wo + (size_t)(tileN + row) * 1024 + scol;
    la[j] = As + cid * 512;
    lb[j] = Bs + cid * 512;
  }
  const bf16* pA[4]; const bf16* pB[4];
#pragma unroll
  for (int f = 0; f < 4; ++f) {
    pA[f] = As + (wm * 64 + f * 16 + r) * 32 + q * 8;
    pB[f] = Bs + (wn * 64 + f * 16 + r) * 32 + q * 8;
  }

  f32x4 acc[4][4];
#pragma unroll
  for (int i = 0; i < 4; ++i)
#pragma unroll
    for (int j = 0; j < 4; ++j) acc[i][j] = (f32x4){0.f, 0.f, 0.f, 0.f};

  auto STAGE = [&](int buf, int k0) {
    const int bo = buf * 4096;
#pragma unroll
    for (int j = 0; j < 2; ++j) {
      gload_lds16(ga[j] + k0, la[j] + bo);
      gload_lds16(gb[j] + k0, lb[j] + bo);
    }
  };
  auto COMPUTE = [&](int buf) {
    const int bo = buf * 4096;
    bf16x8 af[4];
#pragma unroll
    for (int fm = 0; fm < 4; ++fm) af[fm] = *(const bf16x8*)(pA[fm] + bo);
#pragma unroll
    for (int fn = 0; fn < 4; ++fn) {
      bf16x8 b8 = *(const bf16x8*)(pB[fn] + bo);
#pragma unroll
      for (int fm = 0; fm < 4; ++fm)
        acc[fm][fn] = __builtin_amdgcn_mfma_f32_16x16x32_bf16(af[fm], b8, acc[fm][fn], 0, 0, 0);
    }
  };

  STAGE(0, 0);
  int cur = 0;
  for (int t = 0; t < 31; ++t) {
    __syncthreads();
    STAGE(cur ^ 1, (t + 1) * 32);
    COMPUTE(cur);
    cur ^= 1;
  }
  __syncthreads();
  COMPUTE(cur);

#pragma unroll
  for (int fn = 0; fn < 4; ++fn) {
    const int n = tileN + wn * 64 + fn * 16 + r;
    const float bov = bof[n];
#pragma unroll
    for (int fm = 0; fm < 4; ++fm) {
      const int m0 = tileM + wm * 64 + fm * 16 + q * 4;
#pragma unroll
      for (int i = 0; i < 4; ++i)
        O[(size_t)(m0 + i) * 1024 + n] = acc[fm][fn][i] + bov;   // fp32 store
    }
  }
}

// ---------------- out check (wave-parallel) + scalar fallback -----------------
__global__ __launch_bounds__(256)
void chk_out(const bf16* __restrict__ H, const bf16* __restrict__ Wo,
             const float* __restrict__ bof, const float* __restrict__ O,
             int* __restrict__ badB) {
  const int w = (blockIdx.x * 256 + threadIdx.x) >> 6;   // 0..1023 (grid 256)
  const int lane = threadIdx.x & 63;
  const int m = (w * 12347) & 32767;
  const int n = (w * 4099) & 1023;
  float acc = 0.f;
  for (int k = lane; k < 1024; k += 64)
    acc = fmaf((float)H[(size_t)m * 1024 + k], (float)Wo[(size_t)n * 1024 + k], acc);
#pragma unroll
  for (int off = 32; off; off >>= 1) acc += __shfl_xor(acc, off);
  if (lane == 0) {
    acc += bof[n];
    int ok = fabsf(O[(size_t)m * 1024 + n] - acc) <= 0.05f;
    if (!ok) atomicAdd(badB, 1);
  }
}

__global__ __launch_bounds__(256)
void fb_out(const int* __restrict__ badB, const bf16* __restrict__ H,
            const bf16* __restrict__ Wo, const float* __restrict__ bof,
            float* __restrict__ O) {
  if (*badB < 4) return;
  const int n = (blockIdx.x & 3) * 256 + threadIdx.x;
  const int m0 = (blockIdx.x >> 2) * 16;
  for (int mi = 0; mi < 16; ++mi) {
    const int m = m0 + mi;
    float acc = 0.f;
    for (int k = 0; k < 1024; ++k)
      acc = fmaf((float)H[(size_t)m * 1024 + k], (float)Wo[(size_t)n * 1024 + k], acc);
    O[(size_t)m * 1024 + n] = acc + bof[n];
  }
}

// ------------------------------- launch ---------------------------------------
extern "C" void kernel_launch(void* const* d_in, const int* in_sizes, int n_in,
                              void* d_out, int out_size, void* d_ws, size_t ws_size,
                              hipStream_t stream) {
  char* ws = (char*)d_ws;
  // ws: aB 0(64MB) | vB 64MB(64MB, ->h in-place) | Ac 128MB(2MB) | Vc | Hin
  //     | flags 134MB(8B) | wzb +16KB(2MB) | whb | wob | xb 142MB(64MB) ~206MB
  bf16*  aB  = (bf16*)(ws);
  bf16*  vB  = (bf16*)(ws + 67108864ull);
  float* Ac  = (float*)(ws + 134217728ull);
  float* Vc  = (float*)(ws + 136314880ull);
  float* Hin = (float*)(ws + 138412032ull);
  int*   flags = (int*)(ws + 140509184ull);   // [0]=badA, [1]=badB
  bf16*  wzb = (bf16*)(ws + 140525568ull);
  bf16*  whb = wzb + 1048576;
  bf16*  wob = whb + 1048576;
  bf16*  xb  = (bf16*)(ws + 148914176ull);

  const float* bzf = (const float*)d_in[2];
  const float* bhf = (const float*)d_in[4];
  const float* bof = (const float*)d_in[6];

  hipMemsetAsync(flags, 0, 8, stream);
  // x: 8*4096*1024 = 33554432 floats -> n4 = 8388608 (grid-stride)
  conv_b<<<4096, 256, 0, stream>>>((const float*)d_in[0], xb, 8388608);
  conv_w3<<<3072, 256, 0, stream>>>((const float*)d_in[1], (const float*)d_in[3],
                                    (const float*)d_in[5], wzb, whb, wob);

  dim3 blk(256);
  dim3 gg(8, 256);  // (N/128, M/128), M=32768 N=1024 — remapped in-kernel

  gate_gemm<<<gg, blk, 0, stream>>>(xb, wzb, whb, bzf, bhf, aB, vB);
  chk_gate<<<256, blk, 0, stream>>>(xb, wzb, whb, bzf, bhf, aB, vB, flags);
  fb_gate<<<8192, blk, 0, stream>>>(flags, xb, wzb, whb, bzf, bhf, aB, vB);

  scan_phase1<<<256, blk, 0, stream>>>(aB, vB, Ac, Vc);
  scan_phase2<<<32,  blk, 0, stream>>>(Ac, Vc, Hin);
  scan_phase3<<<256, blk, 0, stream>>>(aB, vB, Hin, vB /* in-place h */);

  out_gemm<<<gg, blk, 0, stream>>>(vB, wob, bof, (float*)d_out);
  chk_out<<<256, blk, 0, stream>>>(vB, wob, bof, (const float*)d_out, flags + 1);
  fb_out<<<8192, blk, 0, stream>>>(flags + 1, vB, wob, bof, (float*)d_out);
}

// Round 3
// 605.315 us; speedup vs baseline: 1.1617x; 1.0252x over previous
//
#include <hip/hip_runtime.h>
#include <stdint.h>
#include <stddef.h>

// MinGRU: B=8, S=4096, DX=DH=1024. fp32 in, fp32 out.
// R9 = R8 with the workspace-overlap bug fixed (wob [144719872,146817024)
// overlapped xb@146800640 by 16KB -> X rows 0-7 clobbered by Wo, scan b=0
// poisoned; checker sampling missed rows 0-7). Fixes:
//  1. xb -> ws+146817024 (exactly after wob; no overlap, ~204MB total).
//  2. chk_gate/chk_out now explicitly probe boundary rows (m=0..63 and
//     m=32704..32767) in addition to pseudo-random samples -> buffer-boundary
//     corruption cannot evade the fallback trigger.
// R8 design (unchanged, still being tested): gate GEMM as single standard
// GEMM via row-interleaved W2[2048][1024] (row 2n=Wz[n], 2n+1=Wh[n]);
// single acc[4][4] -> launch_bounds(256,3); (k,th) in adjacent lanes paired
// by shfl_xor(1); activation fused; epilogue LDS-bounce -> full-line bf16x8
// stores (kills 2.27x write amplification). Checkers vs ORIGINAL fp32 inputs.

typedef __bf16 bf16;
typedef __bf16 bf16x8 __attribute__((ext_vector_type(8)));
typedef float f32x4 __attribute__((ext_vector_type(4)));

#define DEV __device__ __forceinline__

DEV void gload_lds16(const bf16* g, bf16* l) {
  // per-lane gptr; LDS dest = wave-uniform base + lane*16B (implicit scatter)
  __builtin_amdgcn_global_load_lds((const __attribute__((address_space(1))) void*)g,
                                   (__attribute__((address_space(3))) void*)l,
                                   16, 0, 0);
}

// XCD-chunked bijective swizzle; grid (2^lg, 256), nwg divisible by 8.
// XCD d&7 owns M-tiles [32j,32j+32), N-tile fastest within.
DEV void xcd_tiles(int bx, int by, int gx_lg, int& tileM, int& tileN) {
  const int d = (by << gx_lg) + bx;
  const int xcd = d & 7;
  const int i = d >> 3;
  tileM = (xcd * 32 + (i >> gx_lg)) * 128;
  tileN = (i & ((1 << gx_lg) - 1)) * 128;
}

// boundary-covering sampler: rows 0..63, rows 32767..32704, then random
DEV void chk_sample(int w, int& m, int& n) {
  if (w < 64)       { m = w;              n = (w * 97) & 1023; }
  else if (w < 128) { m = 32767 - (w - 64); n = (w * 97) & 1023; }
  else              { m = (w * 12347) & 32767; n = (w * 4099) & 1023; }
}

// ---------------- fp32 -> bf16 conversion (grid-stride) -----------------------
__global__ __launch_bounds__(256)
void conv_b(const float* __restrict__ src, bf16* __restrict__ dst, int n4) {
  const int stride = gridDim.x * 256;
  for (int i = blockIdx.x * 256 + threadIdx.x; i < n4; i += stride) {
    float4 v = ((const float4*)src)[i];
    bf16 o[4] = {(bf16)v.x, (bf16)v.y, (bf16)v.z, (bf16)v.w};
    *(uint64_t*)(dst + 4 * (size_t)i) = *(uint64_t*)o;
  }
}

// Wz,Wh -> row-interleaved W2[2048][1024]; Wo -> wob. 786432 float4 groups.
__global__ __launch_bounds__(256)
void conv_w3(const float* __restrict__ wz, const float* __restrict__ wh,
             const float* __restrict__ wo,
             bf16* __restrict__ w2, bf16* __restrict__ wob) {
  const int stride = gridDim.x * 256;
  for (int i = blockIdx.x * 256 + threadIdx.x; i < 786432; i += stride) {
    if (i < 262144) {
      const int j = i, n = j >> 8, c = j & 255;        // 256 float4 per row
      float4 v = ((const float4*)wz)[j];
      bf16 o[4] = {(bf16)v.x, (bf16)v.y, (bf16)v.z, (bf16)v.w};
      *(uint64_t*)(w2 + 4 * ((size_t)(n << 9) + c)) = *(uint64_t*)o;          // row 2n
    } else if (i < 524288) {
      const int j = i - 262144, n = j >> 8, c = j & 255;
      float4 v = ((const float4*)wh)[j];
      bf16 o[4] = {(bf16)v.x, (bf16)v.y, (bf16)v.z, (bf16)v.w};
      *(uint64_t*)(w2 + 4 * ((size_t)(n << 9) + 256 + c)) = *(uint64_t*)o;    // row 2n+1
    } else {
      const int j = i - 524288;
      float4 v = ((const float4*)wo)[j];
      bf16 o[4] = {(bf16)v.x, (bf16)v.y, (bf16)v.z, (bf16)v.w};
      *(uint64_t*)(wob + 4 * (size_t)j) = *(uint64_t*)o;
    }
  }
}

// ---------------- gate GEMM: C=X*W2^T [32768x2048], fused activation ----------
// avB[m][2n]=a_n=sigmoid(-k), avB[m][2n+1]=v_n=sigmoid(k)*g(th).
__global__ __launch_bounds__(256, 3)
void gate_gemm(const bf16* __restrict__ X, const bf16* __restrict__ W2,
               const float* __restrict__ bzf, const float* __restrict__ bhf,
               bf16* __restrict__ avB) {
  __shared__ __align__(16) bf16 SMEM[17408];   // staging 16384 + C-tile reuse
  bf16* As = SMEM;            // 2 x 128x32
  bf16* Bs = SMEM + 8192;     // 2 x 128x32

  const int lane = threadIdx.x & 63;
  const int wave = threadIdx.x >> 6;
  const int wm = wave >> 1, wn = wave & 1;    // 2x2 waves of 64x64
  int tileM, tileN;
  xcd_tiles(blockIdx.x, blockIdx.y, 4, tileM, tileN);   // grid (16,256)
  const int q = lane >> 4, r = lane & 15;
  const int srow = lane >> 2;
  const int scol = (lane & 3) * 8;

  const bf16* ga[2]; const bf16* gb[2]; bf16* la[2]; bf16* lb[2];
#pragma unroll
  for (int j = 0; j < 2; ++j) {
    const int cid = j * 4 + wave;             // 0..7 -> 16-row chunk
    const int row = cid * 16 + srow;
    ga[j] = X  + (size_t)(tileM + row) * 1024 + scol;
    gb[j] = W2 + (size_t)(tileN + row) * 1024 + scol;
    la[j] = As + cid * 512;                   // wave-uniform LDS base (buf 0)
    lb[j] = Bs + cid * 512;
  }
  const bf16* pA[4]; const bf16* pB[4];
#pragma unroll
  for (int f = 0; f < 4; ++f) {
    pA[f] = As + (wm * 64 + f * 16 + r) * 32 + q * 8;   // A[m=r][k=q*8+j]
    pB[f] = Bs + (wn * 64 + f * 16 + r) * 32 + q * 8;   // B[n=r][k=q*8+j]
  }

  f32x4 acc[4][4];
#pragma unroll
  for (int i = 0; i < 4; ++i)
#pragma unroll
    for (int j = 0; j < 4; ++j) acc[i][j] = (f32x4){0.f, 0.f, 0.f, 0.f};

  auto STAGE = [&](int buf, int k0) {
    const int bo = buf * 4096;
#pragma unroll
    for (int j = 0; j < 2; ++j) {
      gload_lds16(ga[j] + k0, la[j] + bo);
      gload_lds16(gb[j] + k0, lb[j] + bo);
    }
  };
  auto COMPUTE = [&](int buf) {
    const int bo = buf * 4096;
    bf16x8 af[4];
#pragma unroll
    for (int fm = 0; fm < 4; ++fm) af[fm] = *(const bf16x8*)(pA[fm] + bo);
#pragma unroll
    for (int fn = 0; fn < 4; ++fn) {
      bf16x8 b8 = *(const bf16x8*)(pB[fn] + bo);
#pragma unroll
      for (int fm = 0; fm < 4; ++fm)
        acc[fm][fn] = __builtin_amdgcn_mfma_f32_16x16x32_bf16(af[fm], b8, acc[fm][fn], 0, 0, 0);
    }
  };

  STAGE(0, 0);
  int cur = 0;
  for (int t = 0; t < 31; ++t) {
    __syncthreads();
    STAGE(cur ^ 1, (t + 1) * 32);
    COMPUTE(cur);
    cur ^= 1;
  }
  __syncthreads();
  COMPUTE(cur);

  // -------- epilogue: pair (k,th) via shfl_xor(1), activate, LDS bounce ------
  __syncthreads();                     // staging reads drained; reuse SMEM
  bf16* C = SMEM;                      // [128][136] bf16 (136 elems = 17x16B)
  // C/D frag: col=lane&15, row=(lane>>4)*4+i  (m89/m91)
#pragma unroll
  for (int fn = 0; fn < 4; ++fn) {
    const int cl = wn * 64 + fn * 16 + r;          // local col 0..127
    const int n = (tileN + cl) >> 1;               // hidden unit
    const float bz = bzf[n], bh = bhf[n];
#pragma unroll
    for (int fm = 0; fm < 4; ++fm) {
      const int ml = wm * 64 + fm * 16 + q * 4;    // local row base
#pragma unroll
      for (int i = 0; i < 4; ++i) {
        const float val = acc[fm][fn][i];
        const float oth = __shfl_xor(val, 1);      // partner col (same n)
        const float kraw  = (lane & 1) ? oth : val;
        const float thraw = (lane & 1) ? val : oth;
        const float k  = kraw + bz;
        const float th = thraw + bh;
        const float e   = __expf(-k);
        const float inv = 1.f / (1.f + e);         // sigmoid(k)
        const float a   = e * inv;                 // sigmoid(-k)
        const float g   = (th >= 0.f) ? (th + 0.5f)
                                      : (1.f / (1.f + __expf(-th)));
        const float res = (lane & 1) ? (inv * g) : a;
        C[(ml + i) * 136 + cl] = (bf16)res;
      }
    }
  }
  __syncthreads();
  // coalesced write-out: full 256B rows, bf16x8 per lane
  const int tT = threadIdx.x;
#pragma unroll
  for (int p = 0; p < 8; ++p) {
    const int row  = p * 16 + (tT >> 4);
    const int col8 = (tT & 15) * 8;
    bf16x8 v8 = *(const bf16x8*)(C + row * 136 + col8);
    *(bf16x8*)(avB + (size_t)(tileM + row) * 2048 + tileN + col8) = v8;
  }
}

// ---------------- gate check vs ORIGINAL fp32 inputs + fallback ---------------
__global__ __launch_bounds__(256)
void chk_gate(const float* __restrict__ Xf,
              const float* __restrict__ Wzf, const float* __restrict__ Whf,
              const float* __restrict__ bzf, const float* __restrict__ bhf,
              const bf16* __restrict__ avB, int* __restrict__ badA) {
  const int w = (blockIdx.x * 256 + threadIdx.x) >> 6;   // 0..1023 (grid 256)
  const int lane = threadIdx.x & 63;
  int m, n;
  chk_sample(w, m, n);
  float kz = 0.f, kh = 0.f;
  for (int k = lane; k < 1024; k += 64) {
    float xv = Xf[(size_t)m * 1024 + k];
    kz = fmaf(xv, Wzf[(size_t)n * 1024 + k], kz);
    kh = fmaf(xv, Whf[(size_t)n * 1024 + k], kh);
  }
#pragma unroll
  for (int off = 32; off; off >>= 1) {
    kz += __shfl_xor(kz, off);
    kh += __shfl_xor(kh, off);
  }
  if (lane == 0) {
    kz += bzf[n]; kh += bhf[n];
    float e = __expf(-kz), inv = 1.f / (1.f + e);
    float a = e * inv;
    float g = (kh >= 0.f) ? (kh + 0.5f) : (1.f / (1.f + __expf(-kh)));
    float v = inv * g;
    size_t idx = (size_t)m * 2048 + 2 * n;
    int ok = (fabsf((float)avB[idx] - a) <= 0.04f) &&
             (fabsf((float)avB[idx + 1] - v) <= 0.08f);  // NaN -> not ok
    if (!ok) atomicAdd(badA, 1);
  }
}

__global__ __launch_bounds__(256)
void fb_gate(const int* __restrict__ badA, const float* __restrict__ Xf,
             const float* __restrict__ Wzf, const float* __restrict__ Whf,
             const float* __restrict__ bzf, const float* __restrict__ bhf,
             bf16* __restrict__ avB) {
  if (*badA < 4) return;                           // MFMA path OK: no-op
  const int n = (blockIdx.x & 3) * 256 + threadIdx.x;
  const int m0 = (blockIdx.x >> 2) * 16;
  for (int mi = 0; mi < 16; ++mi) {
    const int m = m0 + mi;
    float kz = 0.f, kh = 0.f;
    for (int k = 0; k < 1024; ++k) {
      float xv = Xf[(size_t)m * 1024 + k];
      kz = fmaf(xv, Wzf[(size_t)n * 1024 + k], kz);
      kh = fmaf(xv, Whf[(size_t)n * 1024 + k], kh);
    }
    kz += bzf[n]; kh += bhf[n];
    float e = __expf(-kz), inv = 1.f / (1.f + e);
    float a = e * inv;
    float g = (kh >= 0.f) ? (kh + 0.5f) : (1.f / (1.f + __expf(-kh)));
    size_t idx = (size_t)m * 2048 + 2 * n;
    avB[idx] = (bf16)a;
    avB[idx + 1] = (bf16)(inv * g);
  }
}

// ---------------- scan: h_t = a_t h_{t-1} + v_t, chunks L=64, 8 pairs/thread --
__global__ __launch_bounds__(256)
void scan_phase1(const bf16* __restrict__ avB,
                 float* __restrict__ Ac, float* __restrict__ Vc) {
  const int tid = blockIdx.x * 256 + threadIdx.x;  // B*C*(H/8) = 65536
  const int hg = tid & 127, c = (tid >> 7) & 63, b = tid >> 13;
  const size_t base = (size_t)(b * 4096 + c * 64) * 2048 + hg * 16;
  float A[8], V[8];
#pragma unroll
  for (int j = 0; j < 8; ++j) { A[j] = 1.f; V[j] = 0.f; }
#pragma unroll 8
  for (int t = 0; t < 64; ++t) {
    bf16 arr[16];
    *(bf16x8*)(arr)     = *(const bf16x8*)(avB + base + (size_t)t * 2048);
    *(bf16x8*)(arr + 8) = *(const bf16x8*)(avB + base + (size_t)t * 2048 + 8);
#pragma unroll
    for (int j = 0; j < 8; ++j) {
      float a = (float)arr[2 * j];
      V[j] = fmaf(a, V[j], (float)arr[2 * j + 1]);
      A[j] *= a;
    }
  }
  const size_t o = (size_t)(b * 64 + c) * 1024 + hg * 8;
#pragma unroll
  for (int j = 0; j < 8; ++j) { Ac[o + j] = A[j]; Vc[o + j] = V[j]; }
}

__global__ __launch_bounds__(256)
void scan_phase2(const float* __restrict__ Ac, const float* __restrict__ Vc,
                 float* __restrict__ Hin) {
  const int tid = blockIdx.x * 256 + threadIdx.x;  // B*H = 8192
  const int h = tid & 1023, b = tid >> 10;
  float carry = 0.f;
  for (int c = 0; c < 64; ++c) {
    const int idx = (b * 64 + c) * 1024 + h;
    Hin[idx] = carry;
    carry = fmaf(Ac[idx], carry, Vc[idx]);
  }
}

__global__ __launch_bounds__(256)
void scan_phase3(const bf16* __restrict__ avB, const float* __restrict__ Hin,
                 bf16* __restrict__ hB) {
  const int tid = blockIdx.x * 256 + threadIdx.x;  // 65536
  const int hg = tid & 127, c = (tid >> 7) & 63, b = tid >> 13;
  const size_t base = (size_t)(b * 4096 + c * 64) * 2048 + hg * 16;
  const size_t bout = (size_t)(b * 4096 + c * 64) * 1024 + hg * 8;
  const size_t o = (size_t)(b * 64 + c) * 1024 + hg * 8;
  float hc[8];
#pragma unroll
  for (int j = 0; j < 8; ++j) hc[j] = Hin[o + j];
#pragma unroll 4
  for (int t = 0; t < 64; ++t) {
    bf16 arr[16];
    *(bf16x8*)(arr)     = *(const bf16x8*)(avB + base + (size_t)t * 2048);
    *(bf16x8*)(arr + 8) = *(const bf16x8*)(avB + base + (size_t)t * 2048 + 8);
    bf16x8 h8;
#pragma unroll
    for (int j = 0; j < 8; ++j) {
      hc[j] = fmaf((float)arr[2 * j], hc[j], (float)arr[2 * j + 1]);
      h8[j] = (bf16)hc[j];
    }
    *(bf16x8*)(hB + bout + (size_t)t * 1024) = h8;
  }
}

// ---------------- out GEMM (dbuf DMA staging) -> fp32 output ------------------
__global__ __launch_bounds__(256, 3)
void out_gemm(const bf16* __restrict__ H, const bf16* __restrict__ Wo,
              const float* __restrict__ bof, float* __restrict__ O) {
  __shared__ __align__(16) bf16 As[2 * 4096];
  __shared__ __align__(16) bf16 Bs[2 * 4096];

  const int lane = threadIdx.x & 63;
  const int wave = threadIdx.x >> 6;
  const int wm = wave >> 1, wn = wave & 1;
  int tileM, tileN;
  xcd_tiles(blockIdx.x, blockIdx.y, 3, tileM, tileN);   // grid (8,256)
  const int q = lane >> 4, r = lane & 15;
  const int srow = lane >> 2;
  const int scol = (lane & 3) * 8;

  const bf16* ga[2]; const bf16* gb[2]; bf16* la[2]; bf16* lb[2];
#pragma unroll
  for (int j = 0; j < 2; ++j) {
    const int cid = j * 4 + wave;
    const int row = cid * 16 + srow;
    ga[j] = H  + (size_t)(tileM + row) * 1024 + scol;
    gb[j] = Wo + (size_t)(tileN + row) * 1024 + scol;
    la[j] = As + cid * 512;
    lb[j] = Bs + cid * 512;
  }
  const bf16* pA[4]; const bf16* pB[4];
#pragma unroll
  for (int f = 0; f < 4; ++f) {
    pA[f] = As + (wm * 64 + f * 16 + r) * 32 + q * 8;
    pB[f] = Bs + (wn * 64 + f * 16 + r) * 32 + q * 8;
  }

  f32x4 acc[4][4];
#pragma unroll
  for (int i = 0; i < 4; ++i)
#pragma unroll
    for (int j = 0; j < 4; ++j) acc[i][j] = (f32x4){0.f, 0.f, 0.f, 0.f};

  auto STAGE = [&](int buf, int k0) {
    const int bo = buf * 4096;
#pragma unroll
    for (int j = 0; j < 2; ++j) {
      gload_lds16(ga[j] + k0, la[j] + bo);
      gload_lds16(gb[j] + k0, lb[j] + bo);
    }
  };
  auto COMPUTE = [&](int buf) {
    const int bo = buf * 4096;
    bf16x8 af[4];
#pragma unroll
    for (int fm = 0; fm < 4; ++fm) af[fm] = *(const bf16x8*)(pA[fm] + bo);
#pragma unroll
    for (int fn = 0; fn < 4; ++fn) {
      bf16x8 b8 = *(const bf16x8*)(pB[fn] + bo);
#pragma unroll
      for (int fm = 0; fm < 4; ++fm)
        acc[fm][fn] = __builtin_amdgcn_mfma_f32_16x16x32_bf16(af[fm], b8, acc[fm][fn], 0, 0, 0);
    }
  };

  STAGE(0, 0);
  int cur = 0;
  for (int t = 0; t < 31; ++t) {
    __syncthreads();
    STAGE(cur ^ 1, (t + 1) * 32);
    COMPUTE(cur);
    cur ^= 1;
  }
  __syncthreads();
  COMPUTE(cur);

#pragma unroll
  for (int fn = 0; fn < 4; ++fn) {
    const int n = tileN + wn * 64 + fn * 16 + r;
    const float bov = bof[n];
#pragma unroll
    for (int fm = 0; fm < 4; ++fm) {
      const int m0 = tileM + wm * 64 + fm * 16 + q * 4;
#pragma unroll
      for (int i = 0; i < 4; ++i)
        O[(size_t)(m0 + i) * 1024 + n] = acc[fm][fn][i] + bov;   // full-line fp32
    }
  }
}

// ---------------- out check vs fp32 Wo + fallback -----------------------------
__global__ __launch_bounds__(256)
void chk_out(const bf16* __restrict__ H, const float* __restrict__ Wof,
             const float* __restrict__ bof, const float* __restrict__ O,
             int* __restrict__ badB) {
  const int w = (blockIdx.x * 256 + threadIdx.x) >> 6;
  const int lane = threadIdx.x & 63;
  int m, n;
  chk_sample(w, m, n);
  float acc = 0.f;
  for (int k = lane; k < 1024; k += 64)
    acc = fmaf((float)H[(size_t)m * 1024 + k], Wof[(size_t)n * 1024 + k], acc);
#pragma unroll
  for (int off = 32; off; off >>= 1) acc += __shfl_xor(acc, off);
  if (lane == 0) {
    acc += bof[n];
    int ok = fabsf(O[(size_t)m * 1024 + n] - acc) <= 0.05f;
    if (!ok) atomicAdd(badB, 1);
  }
}

__global__ __launch_bounds__(256)
void fb_out(const int* __restrict__ badB, const bf16* __restrict__ H,
            const float* __restrict__ Wof, const float* __restrict__ bof,
            float* __restrict__ O) {
  if (*badB < 4) return;
  const int n = (blockIdx.x & 3) * 256 + threadIdx.x;
  const int m0 = (blockIdx.x >> 2) * 16;
  for (int mi = 0; mi < 16; ++mi) {
    const int m = m0 + mi;
    float acc = 0.f;
    for (int k = 0; k < 1024; ++k)
      acc = fmaf((float)H[(size_t)m * 1024 + k], Wof[(size_t)n * 1024 + k], acc);
    O[(size_t)m * 1024 + n] = acc + bof[n];
  }
}

// ------------------------------- launch ---------------------------------------
extern "C" void kernel_launch(void* const* d_in, const int* in_sizes, int n_in,
                              void* d_out, int out_size, void* d_ws, size_t ws_size,
                              hipStream_t stream) {
  char* ws = (char*)d_ws;
  // ws layout (R9: overlap fixed):
  //   avB    0          128MB  (134217728)
  //   Ac     134217728    2MB
  //   Vc     136314880    2MB
  //   Hin    138412032    2MB
  //   flags  140509184    8B (padded to 16KB)
  //   w2b    140525568    4MB  -> ends 144719872
  //   wob    144719872    2MB  -> ends 146817024
  //   xb     146817024   64MB  -> ends 213925888 (~204MB)   [was 146800640: BUG]
  bf16*  avB = (bf16*)(ws);
  float* Ac  = (float*)(ws + 134217728ull);
  float* Vc  = (float*)(ws + 136314880ull);
  float* Hin = (float*)(ws + 138412032ull);
  int*   flags = (int*)(ws + 140509184ull);   // [0]=badA, [1]=badB
  bf16*  w2b = (bf16*)(ws + 140525568ull);    // 2048x1024 interleaved
  bf16*  wob = (bf16*)(ws + 144719872ull);    // 1024x1024
  bf16*  xb  = (bf16*)(ws + 146817024ull);    // X bf16; becomes hB after scan3

  const float* Xf  = (const float*)d_in[0];
  const float* Wzf = (const float*)d_in[1];
  const float* bzf = (const float*)d_in[2];
  const float* Whf = (const float*)d_in[3];
  const float* bhf = (const float*)d_in[4];
  const float* Wof = (const float*)d_in[5];
  const float* bof = (const float*)d_in[6];

  hipMemsetAsync(flags, 0, 8, stream);
  conv_b<<<4096, 256, 0, stream>>>(Xf, xb, 8388608);
  conv_w3<<<3072, 256, 0, stream>>>(Wzf, Whf, Wof, w2b, wob);

  dim3 blk(256);
  dim3 gg(16, 256);  // gate: (N/128=16, M/128=256), N=2048 interleaved
  dim3 go(8, 256);   // out:  (N/128=8,  M/128=256), N=1024

  gate_gemm<<<gg, blk, 0, stream>>>(xb, w2b, bzf, bhf, avB);
  chk_gate<<<256, blk, 0, stream>>>(Xf, Wzf, Whf, bzf, bhf, avB, flags);
  fb_gate<<<8192, blk, 0, stream>>>(flags, Xf, Wzf, Whf, bzf, bhf, avB);

  scan_phase1<<<256, blk, 0, stream>>>(avB, Ac, Vc);
  scan_phase2<<<32,  blk, 0, stream>>>(Ac, Vc, Hin);
  scan_phase3<<<256, blk, 0, stream>>>(avB, Hin, xb /* hB: xb is dead */);

  out_gemm<<<go, blk, 0, stream>>>(xb, wob, bof, (float*)d_out);
  chk_out<<<256, blk, 0, stream>>>(xb, Wof, bof, (const float*)d_out, flags + 1);
  fb_out<<<8192, blk, 0, stream>>>(flags + 1, xb, Wof, bof, (float*)d_out);
}

// Round 4
// 568.676 us; speedup vs baseline: 1.2365x; 1.0644x over previous
//
#include <hip/hip_runtime.h>
#include <stdint.h>
#include <stddef.h>

// MinGRU: B=8, S=4096, DX=DH=1024. fp32 in, fp32 out.
// R10 (from R9 @605us; gate 197us, MfmaUtil 32.6, VALUBusy 61, conflicts 1.7e7):
//  1. Activation epilogue VALU diet: v_rcp_f32 (1 instr) replaces the two
//     full-precision fp32 divides (~10 instr each); branchless g-select.
//  2. scan_phase1 FUSED into gate epilogue: C-tile is already in LDS; each
//     tile covers exactly 2 scan-chunks x 64 hidden units -> 128 threads fold
//     t=0..63 and write Ac/Vc. Kills a 144MB kernel pass. Flag-gated
//     scan_phase1_fb recomputes Ac/Vc from avB if fb_gate fired.
//  3. LDS swizzle (both-sides, rule 21): staging source col16 ^= (row>>1)&3
//     pre-applied to per-lane GLOBAL addr (LDS dest stays linear for
//     global_load_lds); fragment read col q ^= (r>>1)&3. 8-way ds_read_b128
//     conflict -> 2 addrs/bank-group (free). Applied in both GEMMs.
// R9 design retained: single gate GEMM via row-interleaved W2[2048][1024],
// single acc[4][4], bounds(256,3), LDS C-bounce full-line stores, checkers
// vs ORIGINAL fp32 inputs, boundary-covering sampler.

typedef __bf16 bf16;
typedef __bf16 bf16x8 __attribute__((ext_vector_type(8)));
typedef float f32x4 __attribute__((ext_vector_type(4)));

#define DEV __device__ __forceinline__

DEV void gload_lds16(const bf16* g, bf16* l) {
  // per-lane gptr; LDS dest = wave-uniform base + lane*16B (implicit scatter)
  __builtin_amdgcn_global_load_lds((const __attribute__((address_space(1))) void*)g,
                                   (__attribute__((address_space(3))) void*)l,
                                   16, 0, 0);
}

DEV float fast_rcp(float x) {
  float r;
  asm("v_rcp_f32 %0, %1" : "=v"(r) : "v"(x));
  return r;
}

// XCD-chunked bijective swizzle; grid (2^lg, 256), nwg divisible by 8.
DEV void xcd_tiles(int bx, int by, int gx_lg, int& tileM, int& tileN) {
  const int d = (by << gx_lg) + bx;
  const int xcd = d & 7;
  const int i = d >> 3;
  tileM = (xcd * 32 + (i >> gx_lg)) * 128;
  tileN = (i & ((1 << gx_lg) - 1)) * 128;
}

// boundary-covering sampler: rows 0..63, rows 32767..32704, then random
DEV void chk_sample(int w, int& m, int& n) {
  if (w < 64)       { m = w;                 n = (w * 97) & 1023; }
  else if (w < 128) { m = 32767 - (w - 64);  n = (w * 97) & 1023; }
  else              { m = (w * 12347) & 32767; n = (w * 4099) & 1023; }
}

// ---------------- fp32 -> bf16 conversion (grid-stride) -----------------------
__global__ __launch_bounds__(256)
void conv_b(const float* __restrict__ src, bf16* __restrict__ dst, int n4) {
  const int stride = gridDim.x * 256;
  for (int i = blockIdx.x * 256 + threadIdx.x; i < n4; i += stride) {
    float4 v = ((const float4*)src)[i];
    bf16 o[4] = {(bf16)v.x, (bf16)v.y, (bf16)v.z, (bf16)v.w};
    *(uint64_t*)(dst + 4 * (size_t)i) = *(uint64_t*)o;
  }
}

// Wz,Wh -> row-interleaved W2[2048][1024]; Wo -> wob. 786432 float4 groups.
__global__ __launch_bounds__(256)
void conv_w3(const float* __restrict__ wz, const float* __restrict__ wh,
             const float* __restrict__ wo,
             bf16* __restrict__ w2, bf16* __restrict__ wob) {
  const int stride = gridDim.x * 256;
  for (int i = blockIdx.x * 256 + threadIdx.x; i < 786432; i += stride) {
    if (i < 262144) {
      const int j = i, n = j >> 8, c = j & 255;
      float4 v = ((const float4*)wz)[j];
      bf16 o[4] = {(bf16)v.x, (bf16)v.y, (bf16)v.z, (bf16)v.w};
      *(uint64_t*)(w2 + 4 * ((size_t)(n << 9) + c)) = *(uint64_t*)o;          // row 2n
    } else if (i < 524288) {
      const int j = i - 262144, n = j >> 8, c = j & 255;
      float4 v = ((const float4*)wh)[j];
      bf16 o[4] = {(bf16)v.x, (bf16)v.y, (bf16)v.z, (bf16)v.w};
      *(uint64_t*)(w2 + 4 * ((size_t)(n << 9) + 256 + c)) = *(uint64_t*)o;    // row 2n+1
    } else {
      const int j = i - 524288;
      float4 v = ((const float4*)wo)[j];
      bf16 o[4] = {(bf16)v.x, (bf16)v.y, (bf16)v.z, (bf16)v.w};
      *(uint64_t*)(wob + 4 * (size_t)j) = *(uint64_t*)o;
    }
  }
}

// ---------------- gate GEMM: C=X*W2^T [32768x2048], fused act + chunk fold ----
// avB[m][2n]=a_n=sigmoid(-k), avB[m][2n+1]=v_n=sigmoid(k)*g(th).
// Also writes Ac/Vc (per-64-chunk scan reduction) from the LDS C-tile.
__global__ __launch_bounds__(256, 3)
void gate_gemm(const bf16* __restrict__ X, const bf16* __restrict__ W2,
               const float* __restrict__ bzf, const float* __restrict__ bhf,
               bf16* __restrict__ avB,
               float* __restrict__ Ac, float* __restrict__ Vc) {
  __shared__ __align__(16) bf16 SMEM[17408];   // staging 16384; C-tile reuse
  bf16* As = SMEM;            // 2 x 128x32
  bf16* Bs = SMEM + 8192;     // 2 x 128x32

  const int lane = threadIdx.x & 63;
  const int wave = threadIdx.x >> 6;
  const int wm = wave >> 1, wn = wave & 1;    // 2x2 waves of 64x64
  int tileM, tileN;
  xcd_tiles(blockIdx.x, blockIdx.y, 4, tileM, tileN);   // grid (16,256)
  const int q = lane >> 4, r = lane & 15;
  const int srow = lane >> 2;
  // staging col16 swizzle: slot l holds global col16 (l&3)^((l>>3)&3)
  const int scol = (((lane & 3) ^ ((lane >> 3) & 3)) * 8);

  const bf16* ga[2]; const bf16* gb[2]; bf16* la[2]; bf16* lb[2];
#pragma unroll
  for (int j = 0; j < 2; ++j) {
    const int cid = j * 4 + wave;             // 0..7 -> 16-row chunk
    const int row = cid * 16 + srow;
    ga[j] = X  + (size_t)(tileM + row) * 1024 + scol;
    gb[j] = W2 + (size_t)(tileN + row) * 1024 + scol;
    la[j] = As + cid * 512;                   // wave-uniform LDS base (buf 0)
    lb[j] = Bs + cid * 512;
  }
  // fragment read col matches the staging swizzle: q' = q ^ ((r>>1)&3)
  const int q2 = q ^ ((r >> 1) & 3);
  const bf16* pA[4]; const bf16* pB[4];
#pragma unroll
  for (int f = 0; f < 4; ++f) {
    pA[f] = As + (wm * 64 + f * 16 + r) * 32 + q2 * 8;  // A[m=r][k=q*8+j]
    pB[f] = Bs + (wn * 64 + f * 16 + r) * 32 + q2 * 8;  // B[n=r][k=q*8+j]
  }

  f32x4 acc[4][4];
#pragma unroll
  for (int i = 0; i < 4; ++i)
#pragma unroll
    for (int j = 0; j < 4; ++j) acc[i][j] = (f32x4){0.f, 0.f, 0.f, 0.f};

  auto STAGE = [&](int buf, int k0) {
    const int bo = buf * 4096;
#pragma unroll
    for (int j = 0; j < 2; ++j) {
      gload_lds16(ga[j] + k0, la[j] + bo);
      gload_lds16(gb[j] + k0, lb[j] + bo);
    }
  };
  auto COMPUTE = [&](int buf) {
    const int bo = buf * 4096;
    bf16x8 af[4];
#pragma unroll
    for (int fm = 0; fm < 4; ++fm) af[fm] = *(const bf16x8*)(pA[fm] + bo);
#pragma unroll
    for (int fn = 0; fn < 4; ++fn) {
      bf16x8 b8 = *(const bf16x8*)(pB[fn] + bo);
#pragma unroll
      for (int fm = 0; fm < 4; ++fm)
        acc[fm][fn] = __builtin_amdgcn_mfma_f32_16x16x32_bf16(af[fm], b8, acc[fm][fn], 0, 0, 0);
    }
  };

  STAGE(0, 0);
  int cur = 0;
  for (int t = 0; t < 31; ++t) {
    __syncthreads();
    STAGE(cur ^ 1, (t + 1) * 32);
    COMPUTE(cur);
    cur ^= 1;
  }
  __syncthreads();
  COMPUTE(cur);

  // -------- epilogue: pair (k,th) via shfl_xor(1), cheap activation ----------
  __syncthreads();                     // staging reads drained; reuse SMEM
  bf16* C = SMEM;                      // [128][136] bf16
  // C/D frag: col=lane&15, row=(lane>>4)*4+i  (m89/m91)
#pragma unroll
  for (int fn = 0; fn < 4; ++fn) {
    const int cl = wn * 64 + fn * 16 + r;          // local col 0..127
    const int n = (tileN + cl) >> 1;               // hidden unit
    const float bz = bzf[n], bh = bhf[n];
#pragma unroll
    for (int fm = 0; fm < 4; ++fm) {
      const int ml = wm * 64 + fm * 16 + q * 4;    // local row base
#pragma unroll
      for (int i = 0; i < 4; ++i) {
        const float val = acc[fm][fn][i];
        const float oth = __shfl_xor(val, 1);      // partner col (same n)
        const float kv = ((lane & 1) ? oth : val) + bz;
        const float th = ((lane & 1) ? val : oth) + bh;
        const float e   = __expf(-kv);
        const float inv = fast_rcp(1.f + e);       // sigmoid(k), 1-ulp rcp
        const float a   = e * inv;                 // sigmoid(-k)
        const float eh  = __expf(-th);
        const float sg  = fast_rcp(1.f + eh);      // sigmoid(th)
        const float g   = (th >= 0.f) ? (th + 0.5f) : sg;   // cndmask
        const float res = (lane & 1) ? (inv * g) : a;
        C[(ml + i) * 136 + cl] = (bf16)res;
      }
    }
  }
  __syncthreads();
  // coalesced write-out: full 256B rows, bf16x8 per lane
  const int tT = threadIdx.x;
#pragma unroll
  for (int p = 0; p < 8; ++p) {
    const int row  = p * 16 + (tT >> 4);
    const int col8 = (tT & 15) * 8;
    bf16x8 v8 = *(const bf16x8*)(C + row * 136 + col8);
    *(bf16x8*)(avB + (size_t)(tileM + row) * 2048 + tileN + col8) = v8;
  }
  // fused scan_phase1: this tile = 2 chunks (64 rows) x 64 hidden units
  if (tT < 128) {
    const int ch = tT >> 6, u = tT & 63;
    const bf16* Cp = C + (ch * 64) * 136 + u * 2;
    float A = 1.f, V = 0.f;
#pragma unroll 8
    for (int t = 0; t < 64; ++t) {
      union { uint32_t u32; bf16 h[2]; } cv;
      cv.u32 = *(const uint32_t*)(Cp + t * 136);
      const float a = (float)cv.h[0], v = (float)cv.h[1];
      V = fmaf(a, V, v);
      A *= a;
    }
    const int b  = tileM >> 12;            // row / 4096
    const int c0 = (tileM & 4095) >> 6;    // first chunk (always even)
    const size_t o = (size_t)(b * 64 + c0 + ch) * 1024 + (tileN >> 1) + u;
    Ac[o] = A; Vc[o] = V;
  }
}

// ---------------- gate check vs ORIGINAL fp32 inputs + fallback ---------------
__global__ __launch_bounds__(256)
void chk_gate(const float* __restrict__ Xf,
              const float* __restrict__ Wzf, const float* __restrict__ Whf,
              const float* __restrict__ bzf, const float* __restrict__ bhf,
              const bf16* __restrict__ avB, int* __restrict__ badA) {
  const int w = (blockIdx.x * 256 + threadIdx.x) >> 6;   // 0..1023 (grid 256)
  const int lane = threadIdx.x & 63;
  int m, n;
  chk_sample(w, m, n);
  float kz = 0.f, kh = 0.f;
  for (int k = lane; k < 1024; k += 64) {
    float xv = Xf[(size_t)m * 1024 + k];
    kz = fmaf(xv, Wzf[(size_t)n * 1024 + k], kz);
    kh = fmaf(xv, Whf[(size_t)n * 1024 + k], kh);
  }
#pragma unroll
  for (int off = 32; off; off >>= 1) {
    kz += __shfl_xor(kz, off);
    kh += __shfl_xor(kh, off);
  }
  if (lane == 0) {
    kz += bzf[n]; kh += bhf[n];
    float e = __expf(-kz), inv = 1.f / (1.f + e);
    float a = e * inv;
    float g = (kh >= 0.f) ? (kh + 0.5f) : (1.f / (1.f + __expf(-kh)));
    float v = inv * g;
    size_t idx = (size_t)m * 2048 + 2 * n;
    int ok = (fabsf((float)avB[idx] - a) <= 0.04f) &&
             (fabsf((float)avB[idx + 1] - v) <= 0.08f);  // NaN -> not ok
    if (!ok) atomicAdd(badA, 1);
  }
}

__global__ __launch_bounds__(256)
void fb_gate(const int* __restrict__ badA, const float* __restrict__ Xf,
             const float* __restrict__ Wzf, const float* __restrict__ Whf,
             const float* __restrict__ bzf, const float* __restrict__ bhf,
             bf16* __restrict__ avB) {
  if (*badA < 4) return;                           // MFMA path OK: no-op
  const int n = (blockIdx.x & 3) * 256 + threadIdx.x;
  const int m0 = (blockIdx.x >> 2) * 16;
  for (int mi = 0; mi < 16; ++mi) {
    const int m = m0 + mi;
    float kz = 0.f, kh = 0.f;
    for (int k = 0; k < 1024; ++k) {
      float xv = Xf[(size_t)m * 1024 + k];
      kz = fmaf(xv, Wzf[(size_t)n * 1024 + k], kz);
      kh = fmaf(xv, Whf[(size_t)n * 1024 + k], kh);
    }
    kz += bzf[n]; kh += bhf[n];
    float e = __expf(-kz), inv = 1.f / (1.f + e);
    float a = e * inv;
    float g = (kh >= 0.f) ? (kh + 0.5f) : (1.f / (1.f + __expf(-kh)));
    size_t idx = (size_t)m * 2048 + 2 * n;
    avB[idx] = (bf16)a;
    avB[idx + 1] = (bf16)(inv * g);
  }
}

// fallback-gated re-derivation of Ac/Vc (only if fb_gate rewrote avB)
__global__ __launch_bounds__(256)
void scan_phase1_fb(const int* __restrict__ badA, const bf16* __restrict__ avB,
                    float* __restrict__ Ac, float* __restrict__ Vc) {
  if (*badA < 4) return;
  const int tid = blockIdx.x * 256 + threadIdx.x;  // B*C*(H/8) = 65536
  const int hg = tid & 127, c = (tid >> 7) & 63, b = tid >> 13;
  const size_t base = (size_t)(b * 4096 + c * 64) * 2048 + hg * 16;
  float A[8], V[8];
#pragma unroll
  for (int j = 0; j < 8; ++j) { A[j] = 1.f; V[j] = 0.f; }
  for (int t = 0; t < 64; ++t) {
    bf16 arr[16];
    *(bf16x8*)(arr)     = *(const bf16x8*)(avB + base + (size_t)t * 2048);
    *(bf16x8*)(arr + 8) = *(const bf16x8*)(avB + base + (size_t)t * 2048 + 8);
#pragma unroll
    for (int j = 0; j < 8; ++j) {
      float a = (float)arr[2 * j];
      V[j] = fmaf(a, V[j], (float)arr[2 * j + 1]);
      A[j] *= a;
    }
  }
  const size_t o = (size_t)(b * 64 + c) * 1024 + hg * 8;
#pragma unroll
  for (int j = 0; j < 8; ++j) { Ac[o + j] = A[j]; Vc[o + j] = V[j]; }
}

__global__ __launch_bounds__(256)
void scan_phase2(const float* __restrict__ Ac, const float* __restrict__ Vc,
                 float* __restrict__ Hin) {
  const int tid = blockIdx.x * 256 + threadIdx.x;  // B*H = 8192
  const int h = tid & 1023, b = tid >> 10;
  float carry = 0.f;
  for (int c = 0; c < 64; ++c) {
    const int idx = (b * 64 + c) * 1024 + h;
    Hin[idx] = carry;
    carry = fmaf(Ac[idx], carry, Vc[idx]);
  }
}

__global__ __launch_bounds__(256)
void scan_phase3(const bf16* __restrict__ avB, const float* __restrict__ Hin,
                 bf16* __restrict__ hB) {
  const int tid = blockIdx.x * 256 + threadIdx.x;  // 65536
  const int hg = tid & 127, c = (tid >> 7) & 63, b = tid >> 13;
  const size_t base = (size_t)(b * 4096 + c * 64) * 2048 + hg * 16;
  const size_t bout = (size_t)(b * 4096 + c * 64) * 1024 + hg * 8;
  const size_t o = (size_t)(b * 64 + c) * 1024 + hg * 8;
  float hc[8];
#pragma unroll
  for (int j = 0; j < 8; ++j) hc[j] = Hin[o + j];
#pragma unroll 4
  for (int t = 0; t < 64; ++t) {
    bf16 arr[16];
    *(bf16x8*)(arr)     = *(const bf16x8*)(avB + base + (size_t)t * 2048);
    *(bf16x8*)(arr + 8) = *(const bf16x8*)(avB + base + (size_t)t * 2048 + 8);
    bf16x8 h8;
#pragma unroll
    for (int j = 0; j < 8; ++j) {
      hc[j] = fmaf((float)arr[2 * j], hc[j], (float)arr[2 * j + 1]);
      h8[j] = (bf16)hc[j];
    }
    *(bf16x8*)(hB + bout + (size_t)t * 1024) = h8;
  }
}

// ---------------- out GEMM (dbuf DMA staging, swizzled LDS) -> fp32 out -------
__global__ __launch_bounds__(256, 3)
void out_gemm(const bf16* __restrict__ H, const bf16* __restrict__ Wo,
              const float* __restrict__ bof, float* __restrict__ O) {
  __shared__ __align__(16) bf16 As[2 * 4096];
  __shared__ __align__(16) bf16 Bs[2 * 4096];

  const int lane = threadIdx.x & 63;
  const int wave = threadIdx.x >> 6;
  const int wm = wave >> 1, wn = wave & 1;
  int tileM, tileN;
  xcd_tiles(blockIdx.x, blockIdx.y, 3, tileM, tileN);   // grid (8,256)
  const int q = lane >> 4, r = lane & 15;
  const int srow = lane >> 2;
  const int scol = (((lane & 3) ^ ((lane >> 3) & 3)) * 8);

  const bf16* ga[2]; const bf16* gb[2]; bf16* la[2]; bf16* lb[2];
#pragma unroll
  for (int j = 0; j < 2; ++j) {
    const int cid = j * 4 + wave;
    const int row = cid * 16 + srow;
    ga[j] = H  + (size_t)(tileM + row) * 1024 + scol;
    gb[j] = Wo + (size_t)(tileN + row) * 1024 + scol;
    la[j] = As + cid * 512;
    lb[j] = Bs + cid * 512;
  }
  const int q2 = q ^ ((r >> 1) & 3);
  const bf16* pA[4]; const bf16* pB[4];
#pragma unroll
  for (int f = 0; f < 4; ++f) {
    pA[f] = As + (wm * 64 + f * 16 + r) * 32 + q2 * 8;
    pB[f] = Bs + (wn * 64 + f * 16 + r) * 32 + q2 * 8;
  }

  f32x4 acc[4][4];
#pragma unroll
  for (int i = 0; i < 4; ++i)
#pragma unroll
    for (int j = 0; j < 4; ++j) acc[i][j] = (f32x4){0.f, 0.f, 0.f, 0.f};

  auto STAGE = [&](int buf, int k0) {
    const int bo = buf * 4096;
#pragma unroll
    for (int j = 0; j < 2; ++j) {
      gload_lds16(ga[j] + k0, la[j] + bo);
      gload_lds16(gb[j] + k0, lb[j] + bo);
    }
  };
  auto COMPUTE = [&](int buf) {
    const int bo = buf * 4096;
    bf16x8 af[4];
#pragma unroll
    for (int fm = 0; fm < 4; ++fm) af[fm] = *(const bf16x8*)(pA[fm] + bo);
#pragma unroll
    for (int fn = 0; fn < 4; ++fn) {
      bf16x8 b8 = *(const bf16x8*)(pB[fn] + bo);
#pragma unroll
      for (int fm = 0; fm < 4; ++fm)
        acc[fm][fn] = __builtin_amdgcn_mfma_f32_16x16x32_bf16(af[fm], b8, acc[fm][fn], 0, 0, 0);
    }
  };

  STAGE(0, 0);
  int cur = 0;
  for (int t = 0; t < 31; ++t) {
    __syncthreads();
    STAGE(cur ^ 1, (t + 1) * 32);
    COMPUTE(cur);
    cur ^= 1;
  }
  __syncthreads();
  COMPUTE(cur);

#pragma unroll
  for (int fn = 0; fn < 4; ++fn) {
    const int n = tileN + wn * 64 + fn * 16 + r;
    const float bov = bof[n];
#pragma unroll
    for (int fm = 0; fm < 4; ++fm) {
      const int m0 = tileM + wm * 64 + fm * 16 + q * 4;
#pragma unroll
      for (int i = 0; i < 4; ++i)
        O[(size_t)(m0 + i) * 1024 + n] = acc[fm][fn][i] + bov;   // full-line fp32
    }
  }
}

// ---------------- out check vs fp32 Wo + fallback -----------------------------
__global__ __launch_bounds__(256)
void chk_out(const bf16* __restrict__ H, const float* __restrict__ Wof,
             const float* __restrict__ bof, const float* __restrict__ O,
             int* __restrict__ badB) {
  const int w = (blockIdx.x * 256 + threadIdx.x) >> 6;
  const int lane = threadIdx.x & 63;
  int m, n;
  chk_sample(w, m, n);
  float acc = 0.f;
  for (int k = lane; k < 1024; k += 64)
    acc = fmaf((float)H[(size_t)m * 1024 + k], Wof[(size_t)n * 1024 + k], acc);
#pragma unroll
  for (int off = 32; off; off >>= 1) acc += __shfl_xor(acc, off);
  if (lane == 0) {
    acc += bof[n];
    int ok = fabsf(O[(size_t)m * 1024 + n] - acc) <= 0.05f;
    if (!ok) atomicAdd(badB, 1);
  }
}

__global__ __launch_bounds__(256)
void fb_out(const int* __restrict__ badB, const bf16* __restrict__ H,
            const float* __restrict__ Wof, const float* __restrict__ bof,
            float* __restrict__ O) {
  if (*badB < 4) return;
  const int n = (blockIdx.x & 3) * 256 + threadIdx.x;
  const int m0 = (blockIdx.x >> 2) * 16;
  for (int mi = 0; mi < 16; ++mi) {
    const int m = m0 + mi;
    float acc = 0.f;
    for (int k = 0; k < 1024; ++k)
      acc = fmaf((float)H[(size_t)m * 1024 + k], Wof[(size_t)n * 1024 + k], acc);
    O[(size_t)m * 1024 + n] = acc + bof[n];
  }
}

// ------------------------------- launch ---------------------------------------
extern "C" void kernel_launch(void* const* d_in, const int* in_sizes, int n_in,
                              void* d_out, int out_size, void* d_ws, size_t ws_size,
                              hipStream_t stream) {
  char* ws = (char*)d_ws;
  // ws layout:
  //   avB    0          128MB  (134217728)
  //   Ac     134217728    2MB
  //   Vc     136314880    2MB
  //   Hin    138412032    2MB
  //   flags  140509184    8B (padded to 16KB)
  //   w2b    140525568    4MB  -> ends 144719872
  //   wob    144719872    2MB  -> ends 146817024
  //   xb     146817024   64MB  -> ends 213925888 (~204MB)
  bf16*  avB = (bf16*)(ws);
  float* Ac  = (float*)(ws + 134217728ull);
  float* Vc  = (float*)(ws + 136314880ull);
  float* Hin = (float*)(ws + 138412032ull);
  int*   flags = (int*)(ws + 140509184ull);   // [0]=badA, [1]=badB
  bf16*  w2b = (bf16*)(ws + 140525568ull);    // 2048x1024 interleaved
  bf16*  wob = (bf16*)(ws + 144719872ull);    // 1024x1024
  bf16*  xb  = (bf16*)(ws + 146817024ull);    // X bf16; becomes hB after scan3

  const float* Xf  = (const float*)d_in[0];
  const float* Wzf = (const float*)d_in[1];
  const float* bzf = (const float*)d_in[2];
  const float* Whf = (const float*)d_in[3];
  const float* bhf = (const float*)d_in[4];
  const float* Wof = (const float*)d_in[5];
  const float* bof = (const float*)d_in[6];

  hipMemsetAsync(flags, 0, 8, stream);
  conv_b<<<4096, 256, 0, stream>>>(Xf, xb, 8388608);
  conv_w3<<<3072, 256, 0, stream>>>(Wzf, Whf, Wof, w2b, wob);

  dim3 blk(256);
  dim3 gg(16, 256);  // gate: (N/128=16, M/128=256), N=2048 interleaved
  dim3 go(8, 256);   // out:  (N/128=8,  M/128=256), N=1024

  gate_gemm<<<gg, blk, 0, stream>>>(xb, w2b, bzf, bhf, avB, Ac, Vc);
  chk_gate<<<256, blk, 0, stream>>>(Xf, Wzf, Whf, bzf, bhf, avB, flags);
  fb_gate<<<8192, blk, 0, stream>>>(flags, Xf, Wzf, Whf, bzf, bhf, avB);
  scan_phase1_fb<<<256, blk, 0, stream>>>(flags, avB, Ac, Vc);

  scan_phase2<<<32,  blk, 0, stream>>>(Ac, Vc, Hin);
  scan_phase3<<<256, blk, 0, stream>>>(avB, Hin, xb /* hB: xb is dead */);

  out_gemm<<<go, blk, 0, stream>>>(xb, wob, bof, (float*)d_out);
  chk_out<<<256, blk, 0, stream>>>(xb, Wof, bof, (const float*)d_out, flags + 1);
  fb_out<<<8192, blk, 0, stream>>>(flags + 1, xb, Wof, bof, (float*)d_out);
}